// Round 17
// baseline (431.584 us; speedup 1.0000x reference)
//
#include <hip/hip_runtime.h>
#include <hip/hip_bf16.h>
#include <math.h>

#define N_NODES 25000
#define N_EDGES 400000
#define NPB 8
#define WL 232
#define NFS 192   // nf row stride (floats): 64 s + 32*4 padded vec

typedef short bf16x8 __attribute__((ext_vector_type(8)));
typedef float f32x4 __attribute__((ext_vector_type(4)));
typedef unsigned short us8 __attribute__((ext_vector_type(8)));

__device__ __forceinline__ float sigmoidf_(float a){ return 1.f/(1.f+__expf(-a)); }
__device__ __forceinline__ float siluf_(float a){ return a/(1.f+__expf(-a)); }
__device__ __forceinline__ unsigned short f2bf(float f){
  unsigned int x = __float_as_uint(f);
  x += 0x7FFFu + ((x>>16)&1u);
  return (unsigned short)(x>>16);
}
__device__ __forceinline__ float bf2f(unsigned short u){
  return __uint_as_float(((unsigned int)u)<<16);
}

// ---------------- K1: node precompute, 8 nodes/block, streamed weights ----------------
// nf[n][0..63] = s1, nf[n][64 + w*4 + c] = v1[w][c] (c<3; slot 3 = pad)
__global__ __launch_bounds__(256) void k_node_pre(
    const float* __restrict__ x, const float* __restrict__ z,
    const float* __restrict__ W1s, const float* __restrict__ Wscs,
    const float* __restrict__ W1v, const float* __restrict__ Wscv,
    float* __restrict__ nf,
    float* __restrict__ scs, float* __restrict__ scv)
{
  __shared__ float sxs[160][NPB + 1];
  __shared__ float zl[NPB];
  int t = threadIdx.x;
  int n0 = blockIdx.x * NPB;
  for (int i = t; i < 160*NPB; i += 256) {
    int nn = i / 160, k = i - nn*160;
    sxs[k][nn] = x[(size_t)(n0+nn)*160 + k];
  }
  if (t < NPB) zl[t] = z[n0+t];
  __syncthreads();

  if (t < 160) {
    const float* wp; int stride; bool to_nf; int j;
    if (t < 64) { wp = W1s + t;       stride = 64; to_nf = true;  j = t;    }
    else        { wp = Wscs + (t-64); stride = 96; to_nf = false; j = t-64; }
    float acc[NPB];
    #pragma unroll
    for (int nn = 0; nn < NPB; ++nn) acc[nn] = 0.f;
    #pragma unroll 8
    for (int k = 0; k < 64; ++k) {
      float w = wp[(size_t)k*stride];
      #pragma unroll
      for (int nn = 0; nn < NPB; ++nn) acc[nn] = fmaf(sxs[k][nn], w, acc[nn]);
    }
    #pragma unroll
    for (int nn = 0; nn < NPB; ++nn) {
      float v = acc[nn] * zl[nn] * 0.125f;
      if (to_nf) nf[(size_t)(n0+nn)*NFS + j] = v;
      else       scs[(size_t)(n0+nn)*96 + j] = v;
    }
  } else {
    int p = t - 160, wI = p/3, c = p - wI*3;
    float aV[NPB], aC[NPB];
    #pragma unroll
    for (int nn = 0; nn < NPB; ++nn) { aV[nn] = 0.f; aC[nn] = 0.f; }
    #pragma unroll 4
    for (int u = 0; u < 32; ++u) {
      float wv = W1v[u*32 + wI];
      float wc = Wscv[u*32 + wI];
      #pragma unroll
      for (int nn = 0; nn < NPB; ++nn) {
        float a = sxs[64 + u*3 + c][nn];
        aV[nn] = fmaf(a, wv, aV[nn]);
        aC[nn] = fmaf(a, wc, aC[nn]);
      }
    }
    #pragma unroll
    for (int nn = 0; nn < NPB; ++nn) {
      float zz = zl[nn] * 0.17677669529663687f;
      nf [(size_t)(n0+nn)*NFS + 64 + wI*4 + c] = aV[nn] * zz;
      scv[(size_t)(n0+nn)*96 + p]              = aC[nn] * zz;
    }
  }
}

// ---------------- K2: histogram of edge_dst ----------------
__global__ __launch_bounds__(256) void k_hist(const int* __restrict__ dst, int* __restrict__ cnt){
  int e = blockIdx.x*256 + threadIdx.x;
  if (e < N_EDGES) atomicAdd(&cnt[dst[e]], 1);
}

// ---------------- K3: exclusive scan (single block) ----------------
__global__ __launch_bounds__(1024) void k_scan(const int* __restrict__ cnt, int* __restrict__ offs, int* __restrict__ cursor){
  __shared__ int ts[1024];
  int t = threadIdx.x;
  const int per = 25;
  int lo = t*per, hi = min(lo+per, N_NODES);
  int s = 0;
  for (int i = lo; i < hi; ++i) s += cnt[i];
  ts[t] = s;
  __syncthreads();
  for (int off = 1; off < 1024; off <<= 1) {
    int v = 0;
    if (t >= off) v = ts[t-off];
    __syncthreads();
    if (t >= off) ts[t] += v;
    __syncthreads();
  }
  int run = ts[t] - s;
  for (int i = lo; i < hi; ++i) { offs[i] = run; cursor[i] = run; run += cnt[i]; }
  if (hi == N_NODES && lo < N_NODES) offs[N_NODES] = run;
}

// ---------------- K4: scatter edge ids to sorted positions (perm/srcs only) ----------------
__global__ __launch_bounds__(256) void k_scatter(const int* __restrict__ src, const int* __restrict__ dst,
    int* __restrict__ cursor, int* __restrict__ perm, int* __restrict__ srcs){
  int e = blockIdx.x*256 + threadIdx.x;
  if (e < N_EDGES) {
    int d = dst[e];
    int p = atomicAdd(&cursor[d], 1);
    perm[p] = e;
    srcs[p] = src[e];
  }
}

// ---------------- K4b: repack Wr2 and Wr1 -> bf16 B-fragment layouts ----------------
__global__ __launch_bounds__(256) void k_prep(const float* __restrict__ Wr2, const float* __restrict__ Wr1,
                                             unsigned short* __restrict__ Wr2bf, unsigned short* __restrict__ Wr1bf){
  int i = blockIdx.x*256 + threadIdx.x;
  if (i < 28672) {
    int j = i & 7, lane = (i>>3)&63, ks = (i>>9)&3, nt = i>>11;
    int k = ks*32 + (lane>>4)*8 + j;
    int n = nt*16 + (lane&15);
    float v = (k < 100) ? Wr2[k*224 + n] : 0.f;
    Wr2bf[i] = f2bf(v);
  }
  int i2 = i - 28672;
  if (i2 >= 0 && i2 < 3584) {
    int j = i2 & 7, lane = (i2>>3)&63, nt = i2>>9;
    int k = (lane>>4)*8 + j;
    int n = nt*16 + (lane&15);
    float v = (k < 12 && n < 100) ? Wr1[k*100 + n] : 0.f;
    Wr1bf[i2] = f2bf(v);
  }
}

// ---------------- K5: edge MLP via MFMA; phase-aliased LDS pool (30 KB) ----------------
// also builds eattr_s (dst-sorted eattr) from the perm value already in registers.
__global__ __launch_bounds__(256) void k_edge_gemm(
    const int* __restrict__ perm,
    const float* __restrict__ es,
    const unsigned short* __restrict__ Wr1bf,
    const unsigned short* __restrict__ Wr2bf,
    const float* __restrict__ eattr,
    unsigned short* __restrict__ wbuf,
    float* __restrict__ eattr_s)
{
  __shared__ int pm[64];
  __shared__ __align__(16) unsigned short pool[64*WL];   // 14848 ushorts = 29696 B
  unsigned short* hs  = pool;           // 64 x 136
  unsigned short* esb = pool + 8704;    // 64 x 40
  unsigned short* wsl = pool;           // 64 x 232 (phase B)
  int t = threadIdx.x;
  int p0 = blockIdx.x * 64;
  if (t < 64) {
    int pe = perm[p0 + t];
    pm[t] = pe;
    float4 ea = *reinterpret_cast<const float4*>(eattr + (size_t)pe*4);
    *reinterpret_cast<float4*>(eattr_s + (size_t)(p0 + t)*4) = ea;
  }
  // zero hs K-pad columns 112..127 (MLP1 writes cols 0..111)
  for (int i = t; i < 64*16; i += 256) {
    int e = i >> 4, c = i & 15;
    hs[e*136 + 112 + c] = 0;
  }
  __syncthreads();
  for (int i = t; i < 2048; i += 256) {
    int e = i >> 5, k = i & 31;
    esb[e*40 + k] = (k < 12) ? f2bf(es[(size_t)pm[e]*12 + k]) : (unsigned short)0;
  }
  __syncthreads();
  int l = t & 63, wid = t >> 6;
  int r16 = l & 15, khi = l >> 4;
  // ---- MLP1 via MFMA: h = silu(es @ Wr1 / sqrt(12)); wave w does rows 16w..16w+15 ----
  {
    bf16x8 a = *(const bf16x8*)&esb[(wid*16 + r16)*40 + khi*8];
    #pragma unroll
    for (int nt = 0; nt < 7; ++nt) {
      f32x4 d = (f32x4){0.f,0.f,0.f,0.f};
      bf16x8 b = *(const bf16x8*)&Wr1bf[(size_t)(nt*64 + l)*8];
      d = __builtin_amdgcn_mfma_f32_16x16x32_bf16(a, b, d, 0, 0, 0);
      #pragma unroll
      for (int r = 0; r < 4; ++r) {
        float aa = d[r] * 0.28867513459481287f;
        float hh = aa / (1.f + __expf(-aa));
        hs[(wid*16 + khi*4 + r)*136 + nt*16 + r16] = f2bf(hh);
      }
    }
  }
  __syncthreads();
  // ---- GEMM2: w = h @ Wr2 / 10, 4 waves as 2M x 2N; results stay in acc regs ----
  int mrow = wid >> 1, ng = wid & 1;
  f32x4 acc[2][7];
  #pragma unroll
  for (int i=0;i<2;i++)
    #pragma unroll
    for (int j=0;j<7;j++) acc[i][j] = (f32x4){0.f,0.f,0.f,0.f};
  #pragma unroll
  for (int ks = 0; ks < 4; ++ks) {
    bf16x8 a0 = *(const bf16x8*)&hs[(mrow*32 + r16)*136 + ks*32 + khi*8];
    bf16x8 a1 = *(const bf16x8*)&hs[(mrow*32 + 16 + r16)*136 + ks*32 + khi*8];
    #pragma unroll
    for (int ni = 0; ni < 7; ++ni) {
      int nt = ng*7 + ni;
      bf16x8 b = *(const bf16x8*)&Wr2bf[(size_t)((nt*4+ks)*64 + l)*8];
      acc[0][ni] = __builtin_amdgcn_mfma_f32_16x16x32_bf16(a0, b, acc[0][ni], 0, 0, 0);
      acc[1][ni] = __builtin_amdgcn_mfma_f32_16x16x32_bf16(a1, b, acc[1][ni], 0, 0, 0);
    }
  }
  // all hs reads done by all waves -> safe to overwrite pool as wsl
  __syncthreads();
  int rowb = mrow*32 + khi*4;
  int colb = ng*112 + r16;
  #pragma unroll
  for (int mi=0;mi<2;mi++)
    #pragma unroll
    for (int ni=0;ni<7;ni++)
      #pragma unroll
      for (int r=0;r<4;r++)
        wsl[(rowb + mi*16 + r)*WL + colb + ni*16] = f2bf(acc[mi][ni][r]*0.1f);
  __syncthreads();
  // ---- coalesced copy: 64 rows x 224 ushorts (28 x 16B chunks per row) ----
  for (int i = t; i < 64*28; i += 256) {
    int e = i / 28, c = i - (i/28)*28;
    us8 v = *reinterpret_cast<const us8*>(&wsl[e*WL + c*8]);
    *reinterpret_cast<us8*>(wbuf + (size_t)(p0 + e)*224 + c*8) = v;
  }
}

// ---------------- K6: 2 waves/node, pair-pipelined gather; float4 nf vec load ----------------
__global__ __launch_bounds__(256) void k_node_out(
    const int* __restrict__ offs, const int* __restrict__ srcs,
    const unsigned short* __restrict__ wbuf,
    const float* __restrict__ nf,
    const float* __restrict__ scs, const float* __restrict__ scv,
    const float* __restrict__ eattr_s, const float* __restrict__ z,
    const float* __restrict__ W2s, const float* __restrict__ W2v,
    float* __restrict__ out, int n_base)
{
  __shared__ float bns[4][96];
  __shared__ float bnv[4][384];
  __shared__ float ysl[2][96];
  __shared__ float yvl[2][96];
  int t = threadIdx.x;
  int wid = t >> 6, l = t & 63, l31 = l & 31;
  int nd0 = wid >> 1, h = wid & 1;
  int n = n_base + blockIdx.x*2 + nd0;
  int lo = offs[n], hi = offs[n+1];
  float accS = 0.f, accS2 = 0.f;
  float aV0=0.f,aV1=0.f,aV2=0.f, aX0=0.f,aX1=0.f,aX2=0.f;

  auto EDGE = [&](int p, int src){
    const unsigned short* wr = wbuf + (size_t)p*224;
    float4 ea = *reinterpret_cast<const float4*>(eattr_s + (size_t)p*4);
    const float* base = nf + (size_t)src*NFS;
    float w1 = bf2f(wr[l]);
    float w2 = bf2f(wr[64+l]);
    float ss = base[l];
    float4 bv = *reinterpret_cast<const float4*>(base + 64 + l31*4);
    float b0 = bv.x, b1 = bv.y, b2 = bv.z;
    float se = ea.x, e0 = ea.y, e1 = ea.z, e2 = ea.w;
    accS = fmaf(w1*ss, se, accS);
    float m = w2*ss;
    aV0 = fmaf(m, e0, aV0); aV1 = fmaf(m, e1, aV1); aV2 = fmaf(m, e2, aV2);
    if (l < 32) {
      float w3 = bf2f(wr[128+l31]);
      float w4 = bf2f(wr[160+l31]);
      accS2 = fmaf(w4, b0*e0 + b1*e1 + b2*e2, accS2);
      float tt = w3*se;
      aX0 = fmaf(tt, b0, aX0); aX1 = fmaf(tt, b1, aX1); aX2 = fmaf(tt, b2, aX2);
    } else {
      float w5 = bf2f(wr[192+l31]);
      aX0 = fmaf(w5, b1*e2 - b2*e1, aX0);
      aX1 = fmaf(w5, b2*e0 - b0*e2, aX1);
      aX2 = fmaf(w5, b0*e1 - b1*e0, aX2);
    }
  };

  int pA = lo + h, pB = pA + 2;
  int srcA = (pA < hi) ? srcs[pA] : 0;
  int srcB = (pB < hi) ? srcs[pB] : 0;
  while (pA < hi) {
    int pA2 = pA + 4, pB2 = pA + 6;
    int srcA2 = (pA2 < hi) ? srcs[pA2] : 0;
    int srcB2 = (pB2 < hi) ? srcs[pB2] : 0;
    EDGE(pA, srcA);
    if (pB < hi) EDGE(pB, srcB);
    pA = pA2; pB = pB2; srcA = srcA2; srcB = srcB2;
  }

  float sc = 0.25f * z[n];
  bns[wid][l] = accS * sc;
  bnv[wid][l*3+0] = aV0*sc; bnv[wid][l*3+1] = aV1*sc; bnv[wid][l*3+2] = aV2*sc;
  if (l < 32) {
    bns[wid][64+l] = accS2 * sc * 0.5773502691896258f;
    bnv[wid][(64+l)*3+0] = aX0*sc; bnv[wid][(64+l)*3+1] = aX1*sc; bnv[wid][(64+l)*3+2] = aX2*sc;
  } else {
    float s2 = sc * 0.7071067811865476f;
    bnv[wid][(96+l31)*3+0] = aX0*s2; bnv[wid][(96+l31)*3+1] = aX1*s2; bnv[wid][(96+l31)*3+2] = aX2*s2;
  }
  __syncthreads();
  for (int i = t; i < 192; i += 256) {
    int nd = i / 96, k = i - nd*96;
    bns[2*nd][k] += bns[2*nd+1][k];
  }
  for (int i = t; i < 768; i += 256) {
    int nd = i / 384, k = i - nd*384;
    bnv[2*nd][k] += bnv[2*nd+1][k];
  }
  __syncthreads();
  for (int task = t; task < 192; task += 256) {
    int nd = task / 96, r = task - nd*96;
    int nn = n_base + blockIdx.x*2 + nd;
    float a = 0.f;
    #pragma unroll 4
    for (int k = 0; k < 96; ++k) a = fmaf(bns[2*nd][k], W2s[k*96 + r], a);
    ysl[nd][r] = 0.3826834323650898f * scs[(size_t)nn*96 + r] + 0.09429304f * a;
  }
  for (int task = t; task < 192; task += 256) {
    int nd = task / 96, idx = task - nd*96;
    int nn = n_base + blockIdx.x*2 + nd;
    int w = idx/3, c = idx - w*3;
    float a = 0.f;
    #pragma unroll 4
    for (int u = 0; u < 128; ++u) a = fmaf(bnv[2*nd][u*3 + c], W2v[u*32 + w], a);
    yvl[nd][idx] = 0.3826834323650898f * scv[(size_t)nn*96 + idx] + 0.08166018f * a;
  }
  __syncthreads();
  for (int task = t; task < 128; task += 256) {
    int nd = task >> 6, r = task & 63;
    int nn = n_base + blockIdx.x*2 + nd;
    out[(size_t)nn*160 + r] = siluf_(ysl[nd][r]);
  }
  for (int task = t; task < 192; task += 256) {
    int nd = task / 96, idx = task - nd*96;
    int nn = n_base + blockIdx.x*2 + nd;
    int w = idx/3;
    out[(size_t)nn*160 + 64 + idx] = yvl[nd][idx] * sigmoidf_(ysl[nd][64+w]);
  }
}

extern "C" void kernel_launch(void* const* d_in, const int* in_sizes, int n_in,
                              void* d_out, int out_size, void* d_ws, size_t ws_size,
                              hipStream_t stream)
{
  const float* x     = (const float*)d_in[0];
  const float* z     = (const float*)d_in[1];
  const int*   esrc  = (const int*)d_in[2];
  const int*   edst  = (const int*)d_in[3];
  const float* eattr = (const float*)d_in[4];
  const float* escal = (const float*)d_in[5];
  const float* Wscs  = (const float*)d_in[6];
  const float* Wscv  = (const float*)d_in[7];
  const float* W1s   = (const float*)d_in[8];
  const float* W1v   = (const float*)d_in[9];
  const float* Wr1   = (const float*)d_in[10];
  const float* Wr2   = (const float*)d_in[11];
  const float* W2s   = (const float*)d_in[12];
  const float* W2v   = (const float*)d_in[13];
  float* out = (float*)d_out;

  char* ws = (char*)d_ws;
  size_t off = 0;
  auto alloc = [&](size_t bytes)->char* {
    char* p = ws + off;
    off = (off + bytes + 255) & ~(size_t)255;
    return p;
  };
  float* nf   = (float*)alloc((size_t)N_NODES*NFS*4);
  float* scs  = (float*)alloc((size_t)N_NODES*96*4);
  float* scv  = (float*)alloc((size_t)N_NODES*96*4);
  unsigned short* wbuf = (unsigned short*)alloc((size_t)N_EDGES*224*2);
  float* eattr_s = (float*)alloc((size_t)N_EDGES*16);
  int* cnt    = (int*)alloc((size_t)N_NODES*4);
  int* offs   = (int*)alloc((size_t)(N_NODES+1)*4);
  int* cursor = (int*)alloc((size_t)N_NODES*4);
  int* perm   = (int*)alloc((size_t)N_EDGES*4);
  int* srcs   = (int*)alloc((size_t)N_EDGES*4);
  unsigned short* Wr2bf = (unsigned short*)alloc((size_t)28672*2);
  unsigned short* Wr1bf = (unsigned short*)alloc((size_t)3584*2);

  hipMemsetAsync(cnt, 0, (size_t)N_NODES*4, stream);
  k_prep<<<126, 256, 0, stream>>>(Wr2, Wr1, Wr2bf, Wr1bf);
  k_node_pre<<<N_NODES/NPB, 256, 0, stream>>>(x, z, W1s, Wscs, W1v, Wscv, nf, scs, scv);
  k_hist<<<(N_EDGES+255)/256, 256, 0, stream>>>(edst, cnt);
  k_scan<<<1, 1024, 0, stream>>>(cnt, offs, cursor);
  k_scatter<<<(N_EDGES+255)/256, 256, 0, stream>>>(esrc, edst, cursor, perm, srcs);
  k_edge_gemm<<<N_EDGES/64, 256, 0, stream>>>(perm, escal, Wr1bf, Wr2bf, eattr, wbuf, eattr_s);
  k_node_out<<<N_NODES/4, 256, 0, stream>>>(offs, srcs, wbuf, nf, scs, scv, eattr_s, z, W2s, W2v, out, 0);
  k_node_out<<<N_NODES/4, 256, 0, stream>>>(offs, srcs, wbuf, nf, scs, scv, eattr_s, z, W2s, W2v, out, N_NODES/2);
}

// Round 18
// 413.013 us; speedup vs baseline: 1.0450x; 1.0450x over previous
//
#include <hip/hip_runtime.h>
#include <hip/hip_bf16.h>
#include <math.h>

#define N_NODES 25000
#define N_EDGES 400000
#define NPB 8
#define WL 232

typedef short bf16x8 __attribute__((ext_vector_type(8)));
typedef float f32x4 __attribute__((ext_vector_type(4)));
typedef unsigned short us8 __attribute__((ext_vector_type(8)));

__device__ __forceinline__ float sigmoidf_(float a){ return 1.f/(1.f+__expf(-a)); }
__device__ __forceinline__ float siluf_(float a){ return a/(1.f+__expf(-a)); }
__device__ __forceinline__ unsigned short f2bf(float f){
  unsigned int x = __float_as_uint(f);
  x += 0x7FFFu + ((x>>16)&1u);
  return (unsigned short)(x>>16);
}
__device__ __forceinline__ float bf2f(unsigned short u){
  return __uint_as_float(((unsigned int)u)<<16);
}

// ---------------- K1: node precompute, 8 nodes/block, streamed weights ----------------
// nf[n][0..63] = s1, nf[n][64..159] = v1 (w*3+c layout)
__global__ __launch_bounds__(256) void k_node_pre(
    const float* __restrict__ x, const float* __restrict__ z,
    const float* __restrict__ W1s, const float* __restrict__ Wscs,
    const float* __restrict__ W1v, const float* __restrict__ Wscv,
    float* __restrict__ nf,
    float* __restrict__ scs, float* __restrict__ scv)
{
  __shared__ float sxs[160][NPB + 1];
  __shared__ float zl[NPB];
  int t = threadIdx.x;
  int n0 = blockIdx.x * NPB;
  for (int i = t; i < 160*NPB; i += 256) {
    int nn = i / 160, k = i - nn*160;
    sxs[k][nn] = x[(size_t)(n0+nn)*160 + k];
  }
  if (t < NPB) zl[t] = z[n0+t];
  __syncthreads();

  if (t < 160) {
    const float* wp; int stride; bool to_nf; int j;
    if (t < 64) { wp = W1s + t;       stride = 64; to_nf = true;  j = t;    }
    else        { wp = Wscs + (t-64); stride = 96; to_nf = false; j = t-64; }
    float acc[NPB];
    #pragma unroll
    for (int nn = 0; nn < NPB; ++nn) acc[nn] = 0.f;
    #pragma unroll 8
    for (int k = 0; k < 64; ++k) {
      float w = wp[(size_t)k*stride];
      #pragma unroll
      for (int nn = 0; nn < NPB; ++nn) acc[nn] = fmaf(sxs[k][nn], w, acc[nn]);
    }
    #pragma unroll
    for (int nn = 0; nn < NPB; ++nn) {
      float v = acc[nn] * zl[nn] * 0.125f;
      if (to_nf) nf[(size_t)(n0+nn)*160 + j] = v;
      else       scs[(size_t)(n0+nn)*96 + j] = v;
    }
  } else {
    int p = t - 160, wI = p/3, c = p - wI*3;
    float aV[NPB], aC[NPB];
    #pragma unroll
    for (int nn = 0; nn < NPB; ++nn) { aV[nn] = 0.f; aC[nn] = 0.f; }
    #pragma unroll 4
    for (int u = 0; u < 32; ++u) {
      float wv = W1v[u*32 + wI];
      float wc = Wscv[u*32 + wI];
      #pragma unroll
      for (int nn = 0; nn < NPB; ++nn) {
        float a = sxs[64 + u*3 + c][nn];
        aV[nn] = fmaf(a, wv, aV[nn]);
        aC[nn] = fmaf(a, wc, aC[nn]);
      }
    }
    #pragma unroll
    for (int nn = 0; nn < NPB; ++nn) {
      float zz = zl[nn] * 0.17677669529663687f;
      nf [(size_t)(n0+nn)*160 + 64 + p] = aV[nn] * zz;
      scv[(size_t)(n0+nn)*96 + p]       = aC[nn] * zz;
    }
  }
}

// ---------------- K2: histogram of edge_dst ----------------
__global__ __launch_bounds__(256) void k_hist(const int* __restrict__ dst, int* __restrict__ cnt){
  int e = blockIdx.x*256 + threadIdx.x;
  if (e < N_EDGES) atomicAdd(&cnt[dst[e]], 1);
}

// ---------------- K3: exclusive scan (single block) ----------------
__global__ __launch_bounds__(1024) void k_scan(const int* __restrict__ cnt, int* __restrict__ offs, int* __restrict__ cursor){
  __shared__ int ts[1024];
  int t = threadIdx.x;
  const int per = 25;
  int lo = t*per, hi = min(lo+per, N_NODES);
  int s = 0;
  for (int i = lo; i < hi; ++i) s += cnt[i];
  ts[t] = s;
  __syncthreads();
  for (int off = 1; off < 1024; off <<= 1) {
    int v = 0;
    if (t >= off) v = ts[t-off];
    __syncthreads();
    if (t >= off) ts[t] += v;
    __syncthreads();
  }
  int run = ts[t] - s;
  for (int i = lo; i < hi; ++i) { offs[i] = run; cursor[i] = run; run += cnt[i]; }
  if (hi == N_NODES && lo < N_NODES) offs[N_NODES] = run;
}

// ---------------- K4: scatter edge ids to sorted positions (perm/srcs only) ----------------
__global__ __launch_bounds__(256) void k_scatter(const int* __restrict__ src, const int* __restrict__ dst,
    int* __restrict__ cursor, int* __restrict__ perm, int* __restrict__ srcs){
  int e = blockIdx.x*256 + threadIdx.x;
  if (e < N_EDGES) {
    int d = dst[e];
    int p = atomicAdd(&cursor[d], 1);
    perm[p] = e;
    srcs[p] = src[e];
  }
}

// ---------------- K4b: repack Wr2 and Wr1 -> bf16 B-fragment layouts ----------------
__global__ __launch_bounds__(256) void k_prep(const float* __restrict__ Wr2, const float* __restrict__ Wr1,
                                             unsigned short* __restrict__ Wr2bf, unsigned short* __restrict__ Wr1bf){
  int i = blockIdx.x*256 + threadIdx.x;
  if (i < 28672) {
    int j = i & 7, lane = (i>>3)&63, ks = (i>>9)&3, nt = i>>11;
    int k = ks*32 + (lane>>4)*8 + j;
    int n = nt*16 + (lane&15);
    float v = (k < 100) ? Wr2[k*224 + n] : 0.f;
    Wr2bf[i] = f2bf(v);
  }
  int i2 = i - 28672;
  if (i2 >= 0 && i2 < 3584) {
    int j = i2 & 7, lane = (i2>>3)&63, nt = i2>>9;
    int k = (lane>>4)*8 + j;
    int n = nt*16 + (lane&15);
    float v = (k < 12 && n < 100) ? Wr1[k*100 + n] : 0.f;
    Wr1bf[i2] = f2bf(v);
  }
}

// w-row block layout for K6: [0-63]=w1, [64-127]=w2, [128-159]=w3, [160-191]=w5, [192-223]=w4
// (swap of the last two 32-col blocks vs the natural GEMM column order)
__device__ __forceinline__ int mapcol(int c){
  return (c < 160) ? c : ((c < 192) ? c + 32 : c - 32);
}

// ---------------- K5: edge MLP via MFMA; phase-aliased LDS pool (30 KB) ----------------
// also builds eattr_s (dst-sorted eattr) from the perm value already in registers.
__global__ __launch_bounds__(256) void k_edge_gemm(
    const int* __restrict__ perm,
    const float* __restrict__ es,
    const unsigned short* __restrict__ Wr1bf,
    const unsigned short* __restrict__ Wr2bf,
    const float* __restrict__ eattr,
    unsigned short* __restrict__ wbuf,
    float* __restrict__ eattr_s)
{
  __shared__ int pm[64];
  __shared__ __align__(16) unsigned short pool[64*WL];   // 14848 ushorts = 29696 B
  unsigned short* hs  = pool;           // 64 x 136
  unsigned short* esb = pool + 8704;    // 64 x 40
  unsigned short* wsl = pool;           // 64 x 232 (phase B)
  int t = threadIdx.x;
  int p0 = blockIdx.x * 64;
  if (t < 64) {
    int pe = perm[p0 + t];
    pm[t] = pe;
    float4 ea = *reinterpret_cast<const float4*>(eattr + (size_t)pe*4);
    *reinterpret_cast<float4*>(eattr_s + (size_t)(p0 + t)*4) = ea;
  }
  // zero hs K-pad columns 112..127 (MLP1 writes cols 0..111)
  for (int i = t; i < 64*16; i += 256) {
    int e = i >> 4, c = i & 15;
    hs[e*136 + 112 + c] = 0;
  }
  __syncthreads();
  for (int i = t; i < 2048; i += 256) {
    int e = i >> 5, k = i & 31;
    esb[e*40 + k] = (k < 12) ? f2bf(es[(size_t)pm[e]*12 + k]) : (unsigned short)0;
  }
  __syncthreads();
  int l = t & 63, wid = t >> 6;
  int r16 = l & 15, khi = l >> 4;
  // ---- MLP1 via MFMA: h = silu(es @ Wr1 / sqrt(12)); wave w does rows 16w..16w+15 ----
  {
    bf16x8 a = *(const bf16x8*)&esb[(wid*16 + r16)*40 + khi*8];
    #pragma unroll
    for (int nt = 0; nt < 7; ++nt) {
      f32x4 d = (f32x4){0.f,0.f,0.f,0.f};
      bf16x8 b = *(const bf16x8*)&Wr1bf[(size_t)(nt*64 + l)*8];
      d = __builtin_amdgcn_mfma_f32_16x16x32_bf16(a, b, d, 0, 0, 0);
      #pragma unroll
      for (int r = 0; r < 4; ++r) {
        float aa = d[r] * 0.28867513459481287f;
        float hh = aa / (1.f + __expf(-aa));
        hs[(wid*16 + khi*4 + r)*136 + nt*16 + r16] = f2bf(hh);
      }
    }
  }
  __syncthreads();
  // ---- GEMM2: w = h @ Wr2 / 10, 4 waves as 2M x 2N; results stay in acc regs ----
  int mrow = wid >> 1, ng = wid & 1;
  f32x4 acc[2][7];
  #pragma unroll
  for (int i=0;i<2;i++)
    #pragma unroll
    for (int j=0;j<7;j++) acc[i][j] = (f32x4){0.f,0.f,0.f,0.f};
  #pragma unroll
  for (int ks = 0; ks < 4; ++ks) {
    bf16x8 a0 = *(const bf16x8*)&hs[(mrow*32 + r16)*136 + ks*32 + khi*8];
    bf16x8 a1 = *(const bf16x8*)&hs[(mrow*32 + 16 + r16)*136 + ks*32 + khi*8];
    #pragma unroll
    for (int ni = 0; ni < 7; ++ni) {
      int nt = ng*7 + ni;
      bf16x8 b = *(const bf16x8*)&Wr2bf[(size_t)((nt*4+ks)*64 + l)*8];
      acc[0][ni] = __builtin_amdgcn_mfma_f32_16x16x32_bf16(a0, b, acc[0][ni], 0, 0, 0);
      acc[1][ni] = __builtin_amdgcn_mfma_f32_16x16x32_bf16(a1, b, acc[1][ni], 0, 0, 0);
    }
  }
  // all hs reads done by all waves -> safe to overwrite pool as wsl
  __syncthreads();
  int rowb = mrow*32 + khi*4;
  int colb = ng*112 + r16;
  #pragma unroll
  for (int mi=0;mi<2;mi++)
    #pragma unroll
    for (int ni=0;ni<7;ni++) {
      int mc = mapcol(colb + ni*16);
      #pragma unroll
      for (int r=0;r<4;r++)
        wsl[(rowb + mi*16 + r)*WL + mc] = f2bf(acc[mi][ni][r]*0.1f);
    }
  __syncthreads();
  // ---- coalesced copy: 64 rows x 224 ushorts (28 x 16B chunks per row) ----
  for (int i = t; i < 64*28; i += 256) {
    int e = i / 28, c = i - (i/28)*28;
    us8 v = *reinterpret_cast<const us8*>(&wsl[e*WL + c*8]);
    *reinterpret_cast<us8*>(wbuf + (size_t)(p0 + e)*224 + c*8) = v;
  }
}

// ---------------- K6: 2 waves/node, pair-pipelined gather; full-wave third w load ----------------
__global__ __launch_bounds__(256) void k_node_out(
    const int* __restrict__ offs, const int* __restrict__ srcs,
    const unsigned short* __restrict__ wbuf,
    const float* __restrict__ nf,
    const float* __restrict__ scs, const float* __restrict__ scv,
    const float* __restrict__ eattr_s, const float* __restrict__ z,
    const float* __restrict__ W2s, const float* __restrict__ W2v,
    float* __restrict__ out)
{
  __shared__ float bns[4][96];
  __shared__ float bnv[4][384];
  __shared__ float ysl[2][96];
  __shared__ float yvl[2][96];
  int t = threadIdx.x;
  int wid = t >> 6, l = t & 63, l31 = l & 31;
  int nd0 = wid >> 1, h = wid & 1;
  int n = blockIdx.x*2 + nd0;
  int lo = offs[n], hi = offs[n+1];
  float accS = 0.f, accS2 = 0.f;
  float aV0=0.f,aV1=0.f,aV2=0.f, aX0=0.f,aX1=0.f,aX2=0.f;

  auto EDGE = [&](int p, int src){
    const unsigned short* wr = wbuf + (size_t)p*224;
    float4 ea = *reinterpret_cast<const float4*>(eattr_s + (size_t)p*4);
    const float* base = nf + (size_t)src*160;
    float w1 = bf2f(wr[l]);
    float w2 = bf2f(wr[64+l]);
    float wA = bf2f(wr[128+l]);        // full-wave 128B: l<32 -> w3[l31], l>=32 -> w5[l31]
    float ss = base[l];
    float b0 = base[64 + l31*3], b1 = base[65 + l31*3], b2 = base[66 + l31*3];
    float se = ea.x, e0 = ea.y, e1 = ea.z, e2 = ea.w;
    accS = fmaf(w1*ss, se, accS);
    float m = w2*ss;
    aV0 = fmaf(m, e0, aV0); aV1 = fmaf(m, e1, aV1); aV2 = fmaf(m, e2, aV2);
    if (l < 32) {
      float w4 = bf2f(wr[192+l31]);    // masked 64B (lanes 0-31 only)
      accS2 = fmaf(w4, b0*e0 + b1*e1 + b2*e2, accS2);
      float tt = wA*se;
      aX0 = fmaf(tt, b0, aX0); aX1 = fmaf(tt, b1, aX1); aX2 = fmaf(tt, b2, aX2);
    } else {
      aX0 = fmaf(wA, b1*e2 - b2*e1, aX0);
      aX1 = fmaf(wA, b2*e0 - b0*e2, aX1);
      aX2 = fmaf(wA, b0*e1 - b1*e0, aX2);
    }
  };

  int pA = lo + h, pB = pA + 2;
  int srcA = (pA < hi) ? srcs[pA] : 0;
  int srcB = (pB < hi) ? srcs[pB] : 0;
  while (pA < hi) {
    int pA2 = pA + 4, pB2 = pA + 6;
    int srcA2 = (pA2 < hi) ? srcs[pA2] : 0;
    int srcB2 = (pB2 < hi) ? srcs[pB2] : 0;
    EDGE(pA, srcA);
    if (pB < hi) EDGE(pB, srcB);
    pA = pA2; pB = pB2; srcA = srcA2; srcB = srcB2;
  }

  float sc = 0.25f * z[n];
  bns[wid][l] = accS * sc;
  bnv[wid][l*3+0] = aV0*sc; bnv[wid][l*3+1] = aV1*sc; bnv[wid][l*3+2] = aV2*sc;
  if (l < 32) {
    bns[wid][64+l] = accS2 * sc * 0.5773502691896258f;
    bnv[wid][(64+l)*3+0] = aX0*sc; bnv[wid][(64+l)*3+1] = aX1*sc; bnv[wid][(64+l)*3+2] = aX2*sc;
  } else {
    float s2 = sc * 0.7071067811865476f;
    bnv[wid][(96+l31)*3+0] = aX0*s2; bnv[wid][(96+l31)*3+1] = aX1*s2; bnv[wid][(96+l31)*3+2] = aX2*s2;
  }
  __syncthreads();
  for (int i = t; i < 192; i += 256) {
    int nd = i / 96, k = i - nd*96;
    bns[2*nd][k] += bns[2*nd+1][k];
  }
  for (int i = t; i < 768; i += 256) {
    int nd = i / 384, k = i - nd*384;
    bnv[2*nd][k] += bnv[2*nd+1][k];
  }
  __syncthreads();
  for (int task = t; task < 192; task += 256) {
    int nd = task / 96, r = task - nd*96;
    int nn = blockIdx.x*2 + nd;
    float a = 0.f;
    #pragma unroll 4
    for (int k = 0; k < 96; ++k) a = fmaf(bns[2*nd][k], W2s[k*96 + r], a);
    ysl[nd][r] = 0.3826834323650898f * scs[(size_t)nn*96 + r] + 0.09429304f * a;
  }
  for (int task = t; task < 192; task += 256) {
    int nd = task / 96, idx = task - nd*96;
    int nn = blockIdx.x*2 + nd;
    int w = idx/3, c = idx - w*3;
    float a = 0.f;
    #pragma unroll 4
    for (int u = 0; u < 128; ++u) a = fmaf(bnv[2*nd][u*3 + c], W2v[u*32 + w], a);
    yvl[nd][idx] = 0.3826834323650898f * scv[(size_t)nn*96 + idx] + 0.08166018f * a;
  }
  __syncthreads();
  for (int task = t; task < 128; task += 256) {
    int nd = task >> 6, r = task & 63;
    int nn = blockIdx.x*2 + nd;
    out[(size_t)nn*160 + r] = siluf_(ysl[nd][r]);
  }
  for (int task = t; task < 192; task += 256) {
    int nd = task / 96, idx = task - nd*96;
    int nn = blockIdx.x*2 + nd;
    int w = idx/3;
    out[(size_t)nn*160 + 64 + idx] = yvl[nd][idx] * sigmoidf_(ysl[nd][64+w]);
  }
}

extern "C" void kernel_launch(void* const* d_in, const int* in_sizes, int n_in,
                              void* d_out, int out_size, void* d_ws, size_t ws_size,
                              hipStream_t stream)
{
  const float* x     = (const float*)d_in[0];
  const float* z     = (const float*)d_in[1];
  const int*   esrc  = (const int*)d_in[2];
  const int*   edst  = (const int*)d_in[3];
  const float* eattr = (const float*)d_in[4];
  const float* escal = (const float*)d_in[5];
  const float* Wscs  = (const float*)d_in[6];
  const float* Wscv  = (const float*)d_in[7];
  const float* W1s   = (const float*)d_in[8];
  const float* W1v   = (const float*)d_in[9];
  const float* Wr1   = (const float*)d_in[10];
  const float* Wr2   = (const float*)d_in[11];
  const float* W2s   = (const float*)d_in[12];
  const float* W2v   = (const float*)d_in[13];
  float* out = (float*)d_out;

  char* ws = (char*)d_ws;
  size_t off = 0;
  auto alloc = [&](size_t bytes)->char* {
    char* p = ws + off;
    off = (off + bytes + 255) & ~(size_t)255;
    return p;
  };
  float* nf   = (float*)alloc((size_t)N_NODES*160*4);
  float* scs  = (float*)alloc((size_t)N_NODES*96*4);
  float* scv  = (float*)alloc((size_t)N_NODES*96*4);
  unsigned short* wbuf = (unsigned short*)alloc((size_t)N_EDGES*224*2);
  float* eattr_s = (float*)alloc((size_t)N_EDGES*16);
  int* cnt    = (int*)alloc((size_t)N_NODES*4);
  int* offs   = (int*)alloc((size_t)(N_NODES+1)*4);
  int* cursor = (int*)alloc((size_t)N_NODES*4);
  int* perm   = (int*)alloc((size_t)N_EDGES*4);
  int* srcs   = (int*)alloc((size_t)N_EDGES*4);
  unsigned short* Wr2bf = (unsigned short*)alloc((size_t)28672*2);
  unsigned short* Wr1bf = (unsigned short*)alloc((size_t)3584*2);

  hipMemsetAsync(cnt, 0, (size_t)N_NODES*4, stream);
  k_prep<<<126, 256, 0, stream>>>(Wr2, Wr1, Wr2bf, Wr1bf);
  k_node_pre<<<N_NODES/NPB, 256, 0, stream>>>(x, z, W1s, Wscs, W1v, Wscv, nf, scs, scv);
  k_hist<<<(N_EDGES+255)/256, 256, 0, stream>>>(edst, cnt);
  k_scan<<<1, 1024, 0, stream>>>(cnt, offs, cursor);
  k_scatter<<<(N_EDGES+255)/256, 256, 0, stream>>>(esrc, edst, cursor, perm, srcs);
  k_edge_gemm<<<N_EDGES/64, 256, 0, stream>>>(perm, escal, Wr1bf, Wr2bf, eattr, wbuf, eattr_s);
  k_node_out<<<N_NODES/2, 256, 0, stream>>>(offs, srcs, wbuf, nf, scs, scv, eattr_s, z, W2s, W2v, out);
}

// Round 19
// 403.309 us; speedup vs baseline: 1.0701x; 1.0241x over previous
//
#include <hip/hip_runtime.h>
#include <hip/hip_bf16.h>
#include <math.h>

#define N_NODES 25000
#define N_EDGES 400000
#define NPB 8
#define WL 232
#define HIST_BLOCKS 1563   // (N_EDGES+255)/256
#define PREP_BLOCKS 126
#define NODEPRE_BLOCKS 3125  // N_NODES/NPB

typedef short bf16x8 __attribute__((ext_vector_type(8)));
typedef float f32x4 __attribute__((ext_vector_type(4)));
typedef unsigned short us8 __attribute__((ext_vector_type(8)));

__device__ __forceinline__ float sigmoidf_(float a){ return 1.f/(1.f+__expf(-a)); }
__device__ __forceinline__ float siluf_(float a){ return a/(1.f+__expf(-a)); }
__device__ __forceinline__ unsigned short f2bf(float f){
  unsigned int x = __float_as_uint(f);
  x += 0x7FFFu + ((x>>16)&1u);
  return (unsigned short)(x>>16);
}
__device__ __forceinline__ float bf2f(unsigned short u){
  return __uint_as_float(((unsigned int)u)<<16);
}

// ---------------- M1: Wr repack (blocks 0..125) + edge_dst histogram (blocks 126..) ----------------
__global__ __launch_bounds__(256) void k_m1(
    const float* __restrict__ Wr2, const float* __restrict__ Wr1,
    unsigned short* __restrict__ Wr2bf, unsigned short* __restrict__ Wr1bf,
    const int* __restrict__ dst, int* __restrict__ cnt)
{
  int t = threadIdx.x;
  if (blockIdx.x < PREP_BLOCKS) {
    int i = blockIdx.x*256 + t;
    if (i < 28672) {
      int j = i & 7, lane = (i>>3)&63, ks = (i>>9)&3, nt = i>>11;
      int k = ks*32 + (lane>>4)*8 + j;
      int n = nt*16 + (lane&15);
      float v = (k < 100) ? Wr2[k*224 + n] : 0.f;
      Wr2bf[i] = f2bf(v);
    }
    int i2 = i - 28672;
    if (i2 >= 0 && i2 < 3584) {
      int j = i2 & 7, lane = (i2>>3)&63, nt = i2>>9;
      int k = (lane>>4)*8 + j;
      int n = nt*16 + (lane&15);
      float v = (k < 12 && n < 100) ? Wr1[k*100 + n] : 0.f;
      Wr1bf[i2] = f2bf(v);
    }
  } else {
    int e = (blockIdx.x - PREP_BLOCKS)*256 + t;
    if (e < N_EDGES) atomicAdd(&cnt[dst[e]], 1);
  }
}

// ---------------- K3: exclusive scan (single block) ----------------
__global__ __launch_bounds__(1024) void k_scan(const int* __restrict__ cnt, int* __restrict__ offs, int* __restrict__ cursor){
  __shared__ int ts[1024];
  int t = threadIdx.x;
  const int per = 25;
  int lo = t*per, hi = min(lo+per, N_NODES);
  int s = 0;
  for (int i = lo; i < hi; ++i) s += cnt[i];
  ts[t] = s;
  __syncthreads();
  for (int off = 1; off < 1024; off <<= 1) {
    int v = 0;
    if (t >= off) v = ts[t-off];
    __syncthreads();
    if (t >= off) ts[t] += v;
    __syncthreads();
  }
  int run = ts[t] - s;
  for (int i = lo; i < hi; ++i) { offs[i] = run; cursor[i] = run; run += cnt[i]; }
  if (hi == N_NODES && lo < N_NODES) offs[N_NODES] = run;
}

// ---------------- M2: edge scatter (blocks 0..1562) + node precompute (blocks 1563..) ----------------
// nf[n][0..63] = s1, nf[n][64..159] = v1 (w*3+c layout)
__global__ __launch_bounds__(256) void k_m2(
    const int* __restrict__ src, const int* __restrict__ dst,
    int* __restrict__ cursor, int* __restrict__ perm, int* __restrict__ srcs,
    const float* __restrict__ x, const float* __restrict__ z,
    const float* __restrict__ W1s, const float* __restrict__ Wscs,
    const float* __restrict__ W1v, const float* __restrict__ Wscv,
    float* __restrict__ nf,
    float* __restrict__ scs, float* __restrict__ scv)
{
  int t = threadIdx.x;
  if (blockIdx.x < HIST_BLOCKS) {
    int e = blockIdx.x*256 + t;
    if (e < N_EDGES) {
      int d = dst[e];
      int p = atomicAdd(&cursor[d], 1);
      perm[p] = e;
      srcs[p] = src[e];
    }
    return;
  }
  __shared__ float sxs[160][NPB + 1];
  __shared__ float zl[NPB];
  int n0 = (blockIdx.x - HIST_BLOCKS) * NPB;
  for (int i = t; i < 160*NPB; i += 256) {
    int nn = i / 160, k = i - nn*160;
    sxs[k][nn] = x[(size_t)(n0+nn)*160 + k];
  }
  if (t < NPB) zl[t] = z[n0+t];
  __syncthreads();

  if (t < 160) {
    const float* wp; int stride; bool to_nf; int j;
    if (t < 64) { wp = W1s + t;       stride = 64; to_nf = true;  j = t;    }
    else        { wp = Wscs + (t-64); stride = 96; to_nf = false; j = t-64; }
    float acc[NPB];
    #pragma unroll
    for (int nn = 0; nn < NPB; ++nn) acc[nn] = 0.f;
    #pragma unroll 8
    for (int k = 0; k < 64; ++k) {
      float w = wp[(size_t)k*stride];
      #pragma unroll
      for (int nn = 0; nn < NPB; ++nn) acc[nn] = fmaf(sxs[k][nn], w, acc[nn]);
    }
    #pragma unroll
    for (int nn = 0; nn < NPB; ++nn) {
      float v = acc[nn] * zl[nn] * 0.125f;
      if (to_nf) nf[(size_t)(n0+nn)*160 + j] = v;
      else       scs[(size_t)(n0+nn)*96 + j] = v;
    }
  } else {
    int p = t - 160, wI = p/3, c = p - wI*3;
    float aV[NPB], aC[NPB];
    #pragma unroll
    for (int nn = 0; nn < NPB; ++nn) { aV[nn] = 0.f; aC[nn] = 0.f; }
    #pragma unroll 4
    for (int u = 0; u < 32; ++u) {
      float wv = W1v[u*32 + wI];
      float wc = Wscv[u*32 + wI];
      #pragma unroll
      for (int nn = 0; nn < NPB; ++nn) {
        float a = sxs[64 + u*3 + c][nn];
        aV[nn] = fmaf(a, wv, aV[nn]);
        aC[nn] = fmaf(a, wc, aC[nn]);
      }
    }
    #pragma unroll
    for (int nn = 0; nn < NPB; ++nn) {
      float zz = zl[nn] * 0.17677669529663687f;
      nf [(size_t)(n0+nn)*160 + 64 + p] = aV[nn] * zz;
      scv[(size_t)(n0+nn)*96 + p]       = aC[nn] * zz;
    }
  }
}

// w-row block layout for K6: [0-63]=w1, [64-127]=w2, [128-159]=w3, [160-191]=w5, [192-223]=w4
__device__ __forceinline__ int mapcol(int c){
  return (c < 160) ? c : ((c < 192) ? c + 32 : c - 32);
}

// ---------------- K5: edge MLP via MFMA; phase-aliased LDS pool (30 KB) ----------------
__global__ __launch_bounds__(256) void k_edge_gemm(
    const int* __restrict__ perm,
    const float* __restrict__ es,
    const unsigned short* __restrict__ Wr1bf,
    const unsigned short* __restrict__ Wr2bf,
    const float* __restrict__ eattr,
    unsigned short* __restrict__ wbuf,
    float* __restrict__ eattr_s)
{
  __shared__ int pm[64];
  __shared__ __align__(16) unsigned short pool[64*WL];   // 14848 ushorts = 29696 B
  unsigned short* hs  = pool;           // 64 x 136
  unsigned short* esb = pool + 8704;    // 64 x 40
  unsigned short* wsl = pool;           // 64 x 232 (phase B)
  int t = threadIdx.x;
  int p0 = blockIdx.x * 64;
  if (t < 64) {
    int pe = perm[p0 + t];
    pm[t] = pe;
    float4 ea = *reinterpret_cast<const float4*>(eattr + (size_t)pe*4);
    *reinterpret_cast<float4*>(eattr_s + (size_t)(p0 + t)*4) = ea;
  }
  for (int i = t; i < 64*16; i += 256) {
    int e = i >> 4, c = i & 15;
    hs[e*136 + 112 + c] = 0;
  }
  __syncthreads();
  for (int i = t; i < 2048; i += 256) {
    int e = i >> 5, k = i & 31;
    esb[e*40 + k] = (k < 12) ? f2bf(es[(size_t)pm[e]*12 + k]) : (unsigned short)0;
  }
  __syncthreads();
  int l = t & 63, wid = t >> 6;
  int r16 = l & 15, khi = l >> 4;
  {
    bf16x8 a = *(const bf16x8*)&esb[(wid*16 + r16)*40 + khi*8];
    #pragma unroll
    for (int nt = 0; nt < 7; ++nt) {
      f32x4 d = (f32x4){0.f,0.f,0.f,0.f};
      bf16x8 b = *(const bf16x8*)&Wr1bf[(size_t)(nt*64 + l)*8];
      d = __builtin_amdgcn_mfma_f32_16x16x32_bf16(a, b, d, 0, 0, 0);
      #pragma unroll
      for (int r = 0; r < 4; ++r) {
        float aa = d[r] * 0.28867513459481287f;
        float hh = aa / (1.f + __expf(-aa));
        hs[(wid*16 + khi*4 + r)*136 + nt*16 + r16] = f2bf(hh);
      }
    }
  }
  __syncthreads();
  int mrow = wid >> 1, ng = wid & 1;
  f32x4 acc[2][7];
  #pragma unroll
  for (int i=0;i<2;i++)
    #pragma unroll
    for (int j=0;j<7;j++) acc[i][j] = (f32x4){0.f,0.f,0.f,0.f};
  #pragma unroll
  for (int ks = 0; ks < 4; ++ks) {
    bf16x8 a0 = *(const bf16x8*)&hs[(mrow*32 + r16)*136 + ks*32 + khi*8];
    bf16x8 a1 = *(const bf16x8*)&hs[(mrow*32 + 16 + r16)*136 + ks*32 + khi*8];
    #pragma unroll
    for (int ni = 0; ni < 7; ++ni) {
      int nt = ng*7 + ni;
      bf16x8 b = *(const bf16x8*)&Wr2bf[(size_t)((nt*4+ks)*64 + l)*8];
      acc[0][ni] = __builtin_amdgcn_mfma_f32_16x16x32_bf16(a0, b, acc[0][ni], 0, 0, 0);
      acc[1][ni] = __builtin_amdgcn_mfma_f32_16x16x32_bf16(a1, b, acc[1][ni], 0, 0, 0);
    }
  }
  __syncthreads();
  int rowb = mrow*32 + khi*4;
  int colb = ng*112 + r16;
  #pragma unroll
  for (int mi=0;mi<2;mi++)
    #pragma unroll
    for (int ni=0;ni<7;ni++) {
      int mc = mapcol(colb + ni*16);
      #pragma unroll
      for (int r=0;r<4;r++)
        wsl[(rowb + mi*16 + r)*WL + mc] = f2bf(acc[mi][ni][r]*0.1f);
    }
  __syncthreads();
  for (int i = t; i < 64*28; i += 256) {
    int e = i / 28, c = i - (i/28)*28;
    us8 v = *reinterpret_cast<const us8*>(&wsl[e*WL + c*8]);
    *reinterpret_cast<us8*>(wbuf + (size_t)(p0 + e)*224 + c*8) = v;
  }
}

// ---------------- K6: 2 waves/node, pair-pipelined gather; full-wave third w load ----------------
__global__ __launch_bounds__(256) void k_node_out(
    const int* __restrict__ offs, const int* __restrict__ srcs,
    const unsigned short* __restrict__ wbuf,
    const float* __restrict__ nf,
    const float* __restrict__ scs, const float* __restrict__ scv,
    const float* __restrict__ eattr_s, const float* __restrict__ z,
    const float* __restrict__ W2s, const float* __restrict__ W2v,
    float* __restrict__ out)
{
  __shared__ float bns[4][96];
  __shared__ float bnv[4][384];
  __shared__ float ysl[2][96];
  __shared__ float yvl[2][96];
  int t = threadIdx.x;
  int wid = t >> 6, l = t & 63, l31 = l & 31;
  int nd0 = wid >> 1, h = wid & 1;
  int n = blockIdx.x*2 + nd0;
  int lo = offs[n], hi = offs[n+1];
  float accS = 0.f, accS2 = 0.f;
  float aV0=0.f,aV1=0.f,aV2=0.f, aX0=0.f,aX1=0.f,aX2=0.f;

  auto EDGE = [&](int p, int src){
    const unsigned short* wr = wbuf + (size_t)p*224;
    float4 ea = *reinterpret_cast<const float4*>(eattr_s + (size_t)p*4);
    const float* base = nf + (size_t)src*160;
    float w1 = bf2f(wr[l]);
    float w2 = bf2f(wr[64+l]);
    float wA = bf2f(wr[128+l]);
    float ss = base[l];
    float b0 = base[64 + l31*3], b1 = base[65 + l31*3], b2 = base[66 + l31*3];
    float se = ea.x, e0 = ea.y, e1 = ea.z, e2 = ea.w;
    accS = fmaf(w1*ss, se, accS);
    float m = w2*ss;
    aV0 = fmaf(m, e0, aV0); aV1 = fmaf(m, e1, aV1); aV2 = fmaf(m, e2, aV2);
    if (l < 32) {
      float w4 = bf2f(wr[192+l31]);
      accS2 = fmaf(w4, b0*e0 + b1*e1 + b2*e2, accS2);
      float tt = wA*se;
      aX0 = fmaf(tt, b0, aX0); aX1 = fmaf(tt, b1, aX1); aX2 = fmaf(tt, b2, aX2);
    } else {
      aX0 = fmaf(wA, b1*e2 - b2*e1, aX0);
      aX1 = fmaf(wA, b2*e0 - b0*e2, aX1);
      aX2 = fmaf(wA, b0*e1 - b1*e0, aX2);
    }
  };

  int pA = lo + h, pB = pA + 2;
  int srcA = (pA < hi) ? srcs[pA] : 0;
  int srcB = (pB < hi) ? srcs[pB] : 0;
  while (pA < hi) {
    int pA2 = pA + 4, pB2 = pA + 6;
    int srcA2 = (pA2 < hi) ? srcs[pA2] : 0;
    int srcB2 = (pB2 < hi) ? srcs[pB2] : 0;
    EDGE(pA, srcA);
    if (pB < hi) EDGE(pB, srcB);
    pA = pA2; pB = pB2; srcA = srcA2; srcB = srcB2;
  }

  float sc = 0.25f * z[n];
  bns[wid][l] = accS * sc;
  bnv[wid][l*3+0] = aV0*sc; bnv[wid][l*3+1] = aV1*sc; bnv[wid][l*3+2] = aV2*sc;
  if (l < 32) {
    bns[wid][64+l] = accS2 * sc * 0.5773502691896258f;
    bnv[wid][(64+l)*3+0] = aX0*sc; bnv[wid][(64+l)*3+1] = aX1*sc; bnv[wid][(64+l)*3+2] = aX2*sc;
  } else {
    float s2 = sc * 0.7071067811865476f;
    bnv[wid][(96+l31)*3+0] = aX0*s2; bnv[wid][(96+l31)*3+1] = aX1*s2; bnv[wid][(96+l31)*3+2] = aX2*s2;
  }
  __syncthreads();
  for (int i = t; i < 192; i += 256) {
    int nd = i / 96, k = i - nd*96;
    bns[2*nd][k] += bns[2*nd+1][k];
  }
  for (int i = t; i < 768; i += 256) {
    int nd = i / 384, k = i - nd*384;
    bnv[2*nd][k] += bnv[2*nd+1][k];
  }
  __syncthreads();
  for (int task = t; task < 192; task += 256) {
    int nd = task / 96, r = task - nd*96;
    int nn = blockIdx.x*2 + nd;
    float a = 0.f;
    #pragma unroll 4
    for (int k = 0; k < 96; ++k) a = fmaf(bns[2*nd][k], W2s[k*96 + r], a);
    ysl[nd][r] = 0.3826834323650898f * scs[(size_t)nn*96 + r] + 0.09429304f * a;
  }
  for (int task = t; task < 192; task += 256) {
    int nd = task / 96, idx = task - nd*96;
    int nn = blockIdx.x*2 + nd;
    int w = idx/3, c = idx - w*3;
    float a = 0.f;
    #pragma unroll 4
    for (int u = 0; u < 128; ++u) a = fmaf(bnv[2*nd][u*3 + c], W2v[u*32 + w], a);
    yvl[nd][idx] = 0.3826834323650898f * scv[(size_t)nn*96 + idx] + 0.08166018f * a;
  }
  __syncthreads();
  for (int task = t; task < 128; task += 256) {
    int nd = task >> 6, r = task & 63;
    int nn = blockIdx.x*2 + nd;
    out[(size_t)nn*160 + r] = siluf_(ysl[nd][r]);
  }
  for (int task = t; task < 192; task += 256) {
    int nd = task / 96, idx = task - nd*96;
    int nn = blockIdx.x*2 + nd;
    int w = idx/3;
    out[(size_t)nn*160 + 64 + idx] = yvl[nd][idx] * sigmoidf_(ysl[nd][64+w]);
  }
}

extern "C" void kernel_launch(void* const* d_in, const int* in_sizes, int n_in,
                              void* d_out, int out_size, void* d_ws, size_t ws_size,
                              hipStream_t stream)
{
  const float* x     = (const float*)d_in[0];
  const float* z     = (const float*)d_in[1];
  const int*   esrc  = (const int*)d_in[2];
  const int*   edst  = (const int*)d_in[3];
  const float* eattr = (const float*)d_in[4];
  const float* escal = (const float*)d_in[5];
  const float* Wscs  = (const float*)d_in[6];
  const float* Wscv  = (const float*)d_in[7];
  const float* W1s   = (const float*)d_in[8];
  const float* W1v   = (const float*)d_in[9];
  const float* Wr1   = (const float*)d_in[10];
  const float* Wr2   = (const float*)d_in[11];
  const float* W2s   = (const float*)d_in[12];
  const float* W2v   = (const float*)d_in[13];
  float* out = (float*)d_out;

  char* ws = (char*)d_ws;
  size_t off = 0;
  auto alloc = [&](size_t bytes)->char* {
    char* p = ws + off;
    off = (off + bytes + 255) & ~(size_t)255;
    return p;
  };
  float* nf   = (float*)alloc((size_t)N_NODES*160*4);
  float* scs  = (float*)alloc((size_t)N_NODES*96*4);
  float* scv  = (float*)alloc((size_t)N_NODES*96*4);
  unsigned short* wbuf = (unsigned short*)alloc((size_t)N_EDGES*224*2);
  float* eattr_s = (float*)alloc((size_t)N_EDGES*16);
  int* cnt    = (int*)alloc((size_t)N_NODES*4);
  int* offs   = (int*)alloc((size_t)(N_NODES+1)*4);
  int* cursor = (int*)alloc((size_t)N_NODES*4);
  int* perm   = (int*)alloc((size_t)N_EDGES*4);
  int* srcs   = (int*)alloc((size_t)N_EDGES*4);
  unsigned short* Wr2bf = (unsigned short*)alloc((size_t)28672*2);
  unsigned short* Wr1bf = (unsigned short*)alloc((size_t)3584*2);

  hipMemsetAsync(cnt, 0, (size_t)N_NODES*4, stream);
  k_m1<<<PREP_BLOCKS + HIST_BLOCKS, 256, 0, stream>>>(Wr2, Wr1, Wr2bf, Wr1bf, edst, cnt);
  k_scan<<<1, 1024, 0, stream>>>(cnt, offs, cursor);
  k_m2<<<HIST_BLOCKS + NODEPRE_BLOCKS, 256, 0, stream>>>(esrc, edst, cursor, perm, srcs,
                                                         x, z, W1s, Wscs, W1v, Wscv, nf, scs, scv);
  k_edge_gemm<<<N_EDGES/64, 256, 0, stream>>>(perm, escal, Wr1bf, Wr2bf, eattr, wbuf, eattr_s);
  k_node_out<<<N_NODES/2, 256, 0, stream>>>(offs, srcs, wbuf, nf, scs, scv, eattr_s, z, W2s, W2v, out);
}